// Round 1
// baseline (12002.354 us; speedup 1.0000x reference)
//
#include <hip/hip_runtime.h>
#include <math.h>
#include <float.h>

#define N_TOT 8192
#define KNB 16
#define ALPHA 0.5f
#define NSPLIT 8
#define CPS (N_TOT/NSPLIT)   // 1024 columns per split

// ---------------------------------------------------------------------------
// A = beta*I + H^T H  (f64 result, chunked-f32 inner accumulation)
// grid (d/32, d/32), block (32,32)
__global__ __launch_bounds__(1024)
void k_ata(const float* __restrict__ H, double* __restrict__ A, int d, double beta) {
    __shared__ float Ha[32][33], Hb[32][33];
    int tx = threadIdx.x, ty = threadIdx.y;
    int a0 = blockIdx.y*32, b0 = blockIdx.x*32;
    double acc = 0.0;
    for (int n0 = 0; n0 < N_TOT; n0 += 32) {
        Ha[ty][tx] = H[(long)(n0+ty)*d + a0+tx];
        Hb[ty][tx] = H[(long)(n0+ty)*d + b0+tx];
        __syncthreads();
        float f = 0.f;
        #pragma unroll
        for (int nn = 0; nn < 32; ++nn)
            f = fmaf(Ha[nn][ty], Hb[nn][tx], f);
        acc += (double)f;
        __syncthreads();
    }
    int a = a0+ty, b = b0+tx;
    A[(long)a*d + b] = acc + ((a==b) ? beta : 0.0);
}

// ---------------------------------------------------------------------------
// Blocked right-looking Cholesky, panel 64, f64.  A holds A then L (lower).
__global__ __launch_bounds__(256)
void k_chol_diag(double* __restrict__ A, int d, int p0) {
    __shared__ double Ad[64][65];
    int tid = threadIdx.x;
    for (int idx = tid; idx < 64*64; idx += 256) {
        int i = idx>>6, j = idx&63;
        Ad[i][j] = A[(long)(p0+i)*d + p0+j];
    }
    __syncthreads();
    for (int j = 0; j < 64; ++j) {
        if (tid == 0) Ad[j][j] = sqrt(Ad[j][j]);
        __syncthreads();
        for (int i = j+1+tid; i < 64; i += 256) Ad[i][j] /= Ad[j][j];
        __syncthreads();
        for (int idx = tid; idx < 64*64; idx += 256) {
            int i = idx>>6, k = idx&63;
            if (i > j && k > j && k <= i)
                Ad[i][k] -= Ad[i][j]*Ad[k][j];
        }
        __syncthreads();
    }
    for (int idx = tid; idx < 64*64; idx += 256) {
        int i = idx>>6, j = idx&63;
        A[(long)(p0+i)*d + p0+j] = (j <= i) ? Ad[i][j] : 0.0;
    }
}

// rows below the panel: L[r, p] = A[r, p] * Lpp^-T   (thread per row, regs)
__global__ __launch_bounds__(256)
void k_trsm(double* __restrict__ A, int d, int p0) {
    __shared__ double Lp[64][65];  // strictly lower of panel diag block
    __shared__ double dg[64];
    int tid = threadIdx.x;
    for (int idx = tid; idx < 64*64; idx += 256) {
        int j = idx>>6, k = idx&63;
        double v = A[(long)(p0+j)*d + p0+k];
        Lp[j][k] = (j > k) ? v : 0.0;
        if (j == k) dg[j] = v;
    }
    __syncthreads();
    int r = p0 + 64 + blockIdx.x*256 + tid;
    if (r >= d) return;
    double* Ar = &A[(long)r*d + p0];
    double v[64];
    #pragma unroll
    for (int j = 0; j < 64; ++j) v[j] = Ar[j];
    #pragma unroll
    for (int k = 0; k < 64; ++k) {
        double lr = v[k] / dg[k];
        Ar[k] = lr;
        #pragma unroll
        for (int j = 0; j < 64; ++j) v[j] -= lr * Lp[j][k];  // Lp[j<=k][k]==0
    }
}

// trailing update A[r,c] -= Lr * Lc^T over the 64 panel columns
__global__ __launch_bounds__(256)
void k_syrk(double* __restrict__ A, int d, int p0) {
    int t0 = p0 + 64;
    int r0 = t0 + blockIdx.y*64, c0 = t0 + blockIdx.x*64;
    __shared__ double Lr[64][33], Lc[64][33];
    int tid = threadIdx.x, tx = tid&15, ty = tid>>4;
    double acc[16];
    #pragma unroll
    for (int i=0;i<16;++i) acc[i]=0.0;
    for (int kc = 0; kc < 64; kc += 32) {
        for (int idx = tid; idx < 64*32; idx += 256) {
            int i = idx>>5, k = idx&31;
            Lr[i][k] = A[(long)(r0+i)*d + p0+kc+k];
            Lc[i][k] = A[(long)(c0+i)*d + p0+kc+k];
        }
        __syncthreads();
        for (int k = 0; k < 32; ++k) {
            double a[4], b[4];
            #pragma unroll
            for (int i=0;i<4;++i){ a[i]=Lr[ty*4+i][k]; b[i]=Lc[tx*4+i][k]; }
            #pragma unroll
            for (int i=0;i<4;++i)
                #pragma unroll
                for (int j=0;j<4;++j) acc[i*4+j] += a[i]*b[j];
        }
        __syncthreads();
    }
    #pragma unroll
    for (int i=0;i<4;++i)
        #pragma unroll
        for (int j=0;j<4;++j)
            A[(long)(r0+ty*4+i)*d + (c0+tx*4+j)] -= acc[i*4+j];
}

// W = L^-T (f64).  One wave per column c of L^-1; W[c][i] = (L^-1)[i][c].
__global__ __launch_bounds__(64)
void k_linv(const double* __restrict__ A, double* __restrict__ W, int d) {
    __shared__ double y[512];
    int c = blockIdx.x, lane = threadIdx.x;
    for (int i = lane; i < c; i += 64) W[(long)c*d + i] = 0.0;
    for (int i = lane; i < d; i += 64) y[i] = 0.0;
    __syncthreads();
    for (int i = c; i < d; ++i) {
        const double* Li = &A[(long)i*d];
        double part = 0.0;
        for (int k = c+lane; k < i; k += 64) part += Li[k]*y[k];
        #pragma unroll
        for (int off=32; off>0; off>>=1) part += __shfl_down(part, off);
        if (lane == 0) {
            double yi = (((i==c)?1.0:0.0) - part)/Li[i];
            y[i] = yi;
            W[(long)c*d + i] = yi;
        }
        __syncthreads();
    }
}

// Z = H @ W  (f32 in, f64 W, f64 accumulate, f32 out). tile 64x64, K-step 32
__global__ __launch_bounds__(256)
void k_hw(const float* __restrict__ H, const double* __restrict__ W,
          float* __restrict__ Z, int d) {
    __shared__ __align__(16) float Ht[32][68];
    __shared__ double Wt[32][66];
    int tid = threadIdx.x, tx = tid&15, ty = tid>>4;
    int r0 = blockIdx.y*64, c0 = blockIdx.x*64;
    double acc[4][4];
    #pragma unroll
    for (int i=0;i<4;++i)
        #pragma unroll
        for (int j=0;j<4;++j) acc[i][j]=0.0;
    for (int k0 = 0; k0 < d; k0 += 32) {
        {
            int row = tid>>2, koff = (tid&3)*8;
            const float* src = &H[(long)(r0+row)*d + k0+koff];
            float4 v0 = *(const float4*)src, v1 = *(const float4*)(src+4);
            Ht[koff+0][row]=v0.x; Ht[koff+1][row]=v0.y; Ht[koff+2][row]=v0.z; Ht[koff+3][row]=v0.w;
            Ht[koff+4][row]=v1.x; Ht[koff+5][row]=v1.y; Ht[koff+6][row]=v1.z; Ht[koff+7][row]=v1.w;
        }
        {
            int k = tid>>3, coff = (tid&7)*8;
            const double* src = &W[(long)(k0+k)*d + c0+coff];
            #pragma unroll
            for (int q=0;q<8;++q) Wt[k][coff+q] = src[q];
        }
        __syncthreads();
        #pragma unroll
        for (int k = 0; k < 32; ++k) {
            float4 av = *(const float4*)&Ht[k][ty*4];
            double a0=av.x, a1=av.y, a2=av.z, a3=av.w;
            double b[4];
            #pragma unroll
            for (int j=0;j<4;++j) b[j] = Wt[k][tx*4+j];
            #pragma unroll
            for (int j=0;j<4;++j) {
                acc[0][j] += a0*b[j]; acc[1][j] += a1*b[j];
                acc[2][j] += a2*b[j]; acc[3][j] += a3*b[j];
            }
        }
        __syncthreads();
    }
    #pragma unroll
    for (int i=0;i<4;++i)
        #pragma unroll
        for (int j=0;j<4;++j)
            Z[(long)(r0+ty*4+i)*d + c0+tx*4+j] = (float)acc[i][j];
}

// sq[n] = sum Z[n]^2 (f64 accum).  One wave per row.
__global__ __launch_bounds__(256)
void k_sq(const float* __restrict__ Z, float* __restrict__ sq, int d) {
    int row = blockIdx.x*4 + (threadIdx.x>>6);
    int lane = threadIdx.x&63;
    const float* z = &Z[(long)row*d];
    double s = 0.0;
    for (int c = lane; c < d; c += 64) { float v = z[c]; s += (double)v*v; }
    #pragma unroll
    for (int off=32; off>0; off>>=1) s += __shfl_down(s, off);
    if (lane==0) sq[row] = (float)s;
}

// ---------------------------------------------------------------------------
// Fused distance GEMM + per-row top-16.  128 rows/block, sweeps 1024 cols.
__global__ __launch_bounds__(256)
void k_topk(const float* __restrict__ Z, const float* __restrict__ sq,
            float* __restrict__ pD, int* __restrict__ pI, int d) {
    __shared__ __align__(16) float At[16][132];
    __shared__ __align__(16) float Bt[16][132];
    __shared__ float d2s[128][33];
    __shared__ float topD[128][16];
    __shared__ int   topI[128][16];
    __shared__ float thrS[128];
    int tid = threadIdx.x, tx = tid&15, ty = tid>>4;
    int r0 = blockIdx.x*128;
    int split = blockIdx.y;
    for (int idx = tid; idx < 128*16; idx += 256) {
        topD[idx>>4][idx&15] = FLT_MAX;
        topI[idx>>4][idx&15] = 0x7fffffff;
    }
    if (tid < 128) thrS[tid] = FLT_MAX;
    float sqr[8];
    #pragma unroll
    for (int i=0;i<8;++i) sqr[i] = sq[r0+ty*8+i];
    __syncthreads();

    for (int ch = 0; ch < CPS/128; ++ch) {
        int c0 = split*CPS + ch*128;
        float acc[8][8];
        #pragma unroll
        for (int i=0;i<8;++i)
            #pragma unroll
            for (int j=0;j<8;++j) acc[i][j]=0.f;
        for (int k0 = 0; k0 < d; k0 += 16) {
            int row = tid>>1, koff = (tid&1)*8;
            {
                const float* sa = &Z[(long)(r0+row)*d + k0+koff];
                float4 a0 = *(const float4*)sa, a1 = *(const float4*)(sa+4);
                At[koff+0][row]=a0.x; At[koff+1][row]=a0.y; At[koff+2][row]=a0.z; At[koff+3][row]=a0.w;
                At[koff+4][row]=a1.x; At[koff+5][row]=a1.y; At[koff+6][row]=a1.z; At[koff+7][row]=a1.w;
            }
            {
                const float* sb = &Z[(long)(c0+row)*d + k0+koff];
                float4 b0 = *(const float4*)sb, b1 = *(const float4*)(sb+4);
                Bt[koff+0][row]=b0.x; Bt[koff+1][row]=b0.y; Bt[koff+2][row]=b0.z; Bt[koff+3][row]=b0.w;
                Bt[koff+4][row]=b1.x; Bt[koff+5][row]=b1.y; Bt[koff+6][row]=b1.z; Bt[koff+7][row]=b1.w;
            }
            __syncthreads();
            #pragma unroll
            for (int k = 0; k < 16; ++k) {
                float4 av0 = *(const float4*)&At[k][ty*8];
                float4 av1 = *(const float4*)&At[k][ty*8+4];
                float4 bv0 = *(const float4*)&Bt[k][tx*8];
                float4 bv1 = *(const float4*)&Bt[k][tx*8+4];
                float a[8] = {av0.x,av0.y,av0.z,av0.w,av1.x,av1.y,av1.z,av1.w};
                float b[8] = {bv0.x,bv0.y,bv0.z,bv0.w,bv1.x,bv1.y,bv1.z,bv1.w};
                #pragma unroll
                for (int i=0;i<8;++i)
                    #pragma unroll
                    for (int j=0;j<8;++j) acc[i][j] = fmaf(a[i], b[j], acc[i][j]);
            }
            __syncthreads();
        }
        float sqc[8];
        #pragma unroll
        for (int j=0;j<8;++j) sqc[j] = sq[c0+tx*8+j];
        // top-k update in 4 column slices of 32
        #pragma unroll
        for (int s = 0; s < 4; ++s) {
            if ((tx>>2) == s) {
                int cbase = tx*8 - s*32;
                #pragma unroll
                for (int i=0;i<8;++i) {
                    float sr = sqr[i];
                    #pragma unroll
                    for (int j=0;j<8;++j)
                        d2s[ty*8+i][cbase+j] = sr + sqc[j] - 2.f*acc[i][j];
                }
            }
            __syncthreads();
            if (tid < 128) {
                int r = tid;
                float th = thrS[r];
                for (int j = 0; j < 32; ++j) {
                    float dv = d2s[r][j];
                    int ci = c0 + s*32 + j;
                    bool ins = (dv < th) || (dv == th && ci < topI[r][15]);
                    if (ins) {
                        int pos = 15;
                        while (pos > 0) {
                            float pd_ = topD[r][pos-1]; int pi_ = topI[r][pos-1];
                            if (dv < pd_ || (dv == pd_ && ci < pi_)) {
                                topD[r][pos] = pd_; topI[r][pos] = pi_; --pos;
                            } else break;
                        }
                        topD[r][pos] = dv; topI[r][pos] = ci;
                        th = topD[r][15];
                    }
                }
                thrS[r] = th;
            }
            __syncthreads();
        }
    }
    for (int idx = tid; idx < 128*16; idx += 256) {
        int r = idx>>4, k = idx&15;
        long o = ((long)(r0+r)*NSPLIT + split)*16 + k;
        pD[o] = topD[r][k]; pI[o] = topI[r][k];
    }
}

// merge NSPLIT partial sorted top-16 lists; emit final lists + sigma partial
__global__ __launch_bounds__(128)
void k_merge(const float* __restrict__ pD, const int* __restrict__ pI,
             float* __restrict__ tD, int* __restrict__ tI, double* sig_accum) {
    __shared__ float mD[128][17];
    __shared__ int   mI[128][17];
    __shared__ double red[128];
    int tid = threadIdx.x;
    long row = (long)blockIdx.x*128 + tid;
    #pragma unroll
    for (int k=0;k<16;++k){ mD[tid][k]=FLT_MAX; mI[tid][k]=0x7fffffff; }
    for (int s = 0; s < NSPLIT; ++s) {
        const float* pd = &pD[(row*NSPLIT+s)*16];
        const int*   pi = &pI[(row*NSPLIT+s)*16];
        for (int k = 0; k < 16; ++k) {
            float dv = pd[k]; int ci = pi[k];
            float wd = mD[tid][15]; int wi = mI[tid][15];
            if (dv > wd || (dv == wd && ci > wi)) break;  // sorted ascending
            int pos = 15;
            while (pos > 0 && (dv < mD[tid][pos-1] ||
                   (dv == mD[tid][pos-1] && ci < mI[tid][pos-1]))) {
                mD[tid][pos]=mD[tid][pos-1]; mI[tid][pos]=mI[tid][pos-1]; --pos;
            }
            mD[tid][pos]=dv; mI[tid][pos]=ci;
        }
    }
    double psum = 0.0;
    #pragma unroll
    for (int k=0;k<16;++k) {
        float dv = mD[tid][k];
        tD[row*16+k]=dv; tI[row*16+k]=mI[tid][k];
        psum += sqrt((double)fmaxf(dv, 0.f));
    }
    red[tid]=psum; __syncthreads();
    for (int s=64;s>0;s>>=1){ if(tid<s) red[tid]+=red[tid+s]; __syncthreads(); }
    if (tid==0) atomicAdd(sig_accum, red[0]);
}

__global__ void k_sigfin(const double* __restrict__ sig_accum, float* __restrict__ inv2s2) {
    double s = sig_accum[0] / (double)(N_TOT*KNB);
    inv2s2[0] = (float)(1.0/(2.0*s*s));
}

__global__ __launch_bounds__(256)
void k_kern(const float* __restrict__ tD, const int* __restrict__ tI,
            const float* __restrict__ inv2s2,
            float* __restrict__ kern, float* __restrict__ deg) {
    int e = blockIdx.x*256 + threadIdx.x;
    int i = e>>4;
    float d2 = fmaxf(tD[e], 0.f);
    float kv = expf(-d2 * inv2s2[0]);
    kern[e] = kv;
    atomicAdd(&deg[i], 0.5f*kv);
    atomicAdd(&deg[tI[e]], 0.5f*kv);
}

__global__ __launch_bounds__(256)
void k_dis(const float* __restrict__ deg, float* __restrict__ dis) {
    int i = blockIdx.x*256 + threadIdx.x;
    float v = deg[i];
    dis[i] = (v > 0.f) ? (1.0f/sqrtf(v)) : 0.f;
}

__global__ __launch_bounds__(256)
void k_count(const int* __restrict__ tI, int* __restrict__ cnt) {
    int e = blockIdx.x*256 + threadIdx.x;
    atomicAdd(&cnt[tI[e]], 1);
}

__global__ __launch_bounds__(1024)
void k_scan(const int* __restrict__ cnt, int* __restrict__ rowstart) {
    __shared__ int buf[1024];
    __shared__ int carry;
    int tid = threadIdx.x;
    if (tid==0) carry = 0;
    __syncthreads();
    for (int base = 0; base < N_TOT; base += 1024) {
        int v = cnt[base+tid];
        buf[tid]=v; __syncthreads();
        for (int off=1; off<1024; off<<=1) {
            int t = (tid>=off)? buf[tid-off] : 0; __syncthreads();
            buf[tid]+=t; __syncthreads();
        }
        rowstart[base+tid] = carry + buf[tid] - v;
        __syncthreads();
        if (tid==1023) carry += buf[1023];
        __syncthreads();
    }
    if (tid==0) rowstart[N_TOT] = carry;
}

__global__ __launch_bounds__(256)
void k_fill(const int* __restrict__ tI, const float* __restrict__ kern,
            const int* __restrict__ rowstart, int* __restrict__ c2,
            int* __restrict__ in_src, float* __restrict__ in_w) {
    int e = blockIdx.x*256 + threadIdx.x;
    int i = e>>4;
    int j = tI[e];
    int pos = atomicAdd(&c2[j], 1);
    int dst = rowstart[j] + pos;
    in_src[dst] = i; in_w[dst] = kern[e];
}

// generic C = scale * (A[MxK] @ B[KxN]); N multiple of 64, K of 16, M of 64
__global__ __launch_bounds__(256)
void k_gemm(const float* __restrict__ A, const float* __restrict__ B,
            float* __restrict__ C, int M, int N, int Kd, float scale) {
    __shared__ __align__(16) float At[16][68];
    __shared__ __align__(16) float Bt[16][68];
    int tid = threadIdx.x, tx = tid&15, ty = tid>>4;
    int r0 = blockIdx.y*64, c0 = blockIdx.x*64;
    float acc[4][4];
    #pragma unroll
    for (int i=0;i<4;++i)
        #pragma unroll
        for (int j=0;j<4;++j) acc[i][j]=0.f;
    for (int k0 = 0; k0 < Kd; k0 += 16) {
        {
            int row = tid>>2, koff = (tid&3)*4;
            float4 v = *(const float4*)&A[(long)(r0+row)*Kd + k0+koff];
            At[koff+0][row]=v.x; At[koff+1][row]=v.y; At[koff+2][row]=v.z; At[koff+3][row]=v.w;
        }
        {
            int k = tid>>4, coff = (tid&15)*4;
            float4 v = *(const float4*)&B[(long)(k0+k)*N + c0+coff];
            *(float4*)&Bt[k][coff] = v;
        }
        __syncthreads();
        #pragma unroll
        for (int k=0;k<16;++k) {
            float4 a = *(const float4*)&At[k][ty*4];
            float4 b = *(const float4*)&Bt[k][tx*4];
            float ar[4] = {a.x,a.y,a.z,a.w};
            float br[4] = {b.x,b.y,b.z,b.w};
            #pragma unroll
            for (int i=0;i<4;++i)
                #pragma unroll
                for (int j=0;j<4;++j) acc[i][j] = fmaf(ar[i], br[j], acc[i][j]);
        }
        __syncthreads();
    }
    #pragma unroll
    for (int i=0;i<4;++i)
        #pragma unroll
        for (int j=0;j<4;++j)
            C[(long)(r0+ty*4+i)*N + c0+tx*4+j] = scale*acc[i][j];
}

__global__ __launch_bounds__(256)
void k_wsym(const float* __restrict__ w2, float* __restrict__ w2s) {
    int i = blockIdx.x, j = threadIdx.x;
    w2s[i*256+j] = 0.5f*(w2[i*256+j] + w2[j*256+i]);
}

// out[i][c] = tanh( preS[i][c] + dis_i * (sum_out + sum_in) )
__global__ __launch_bounds__(256)
void k_spmm_tanh(const float* __restrict__ P, const float* __restrict__ preS,
                 const float* __restrict__ kern, const int* __restrict__ tI,
                 const float* __restrict__ dis, const int* __restrict__ rowstart,
                 const int* __restrict__ in_src, const float* __restrict__ in_w,
                 float* __restrict__ out) {
    int i = blockIdx.x, c = threadIdx.x;
    float acc = 0.f;
    float di = dis[i];
    #pragma unroll 1
    for (int k = 0; k < 16; ++k) {
        int e = i*16+k;
        int j = tI[e];
        float w = 0.5f*kern[e]*dis[j];
        acc = fmaf(w, P[(long)j*256 + c], acc);
    }
    int s0 = rowstart[i], s1 = rowstart[i+1];
    for (int t = s0; t < s1; ++t) {
        int j = in_src[t];
        float w = 0.5f*in_w[t]*dis[j];
        acc = fmaf(w, P[(long)j*256 + c], acc);
    }
    float pre = preS[(long)i*256+c] + di*acc;
    out[(long)i*256+c] = tanhf(pre);
}

// ---------------------------------------------------------------------------
extern "C" void kernel_launch(void* const* d_in, const int* in_sizes, int n_in,
                              void* d_out, int out_size, void* d_ws, size_t ws_size,
                              hipStream_t stream) {
    const float* x   = (const float*)d_in[0];
    const float* adj = (const float*)d_in[1];
    const float* w1  = (const float*)d_in[2];
    const float* w2  = (const float*)d_in[3];

    char* ws = (char*)d_ws;
    size_t off = 0;
    auto alloc = [&](size_t bytes){ size_t o = off; off += (bytes+255)&~(size_t)255; return o; };
    double* A      = (double*)(ws + alloc((size_t)512*512*8));
    double* W      = (double*)(ws + alloc((size_t)512*512*8));
    double* sigacc = (double*)(ws + alloc(256));
    float*  inv2s2 = (float*)(ws + alloc(256));
    float*  bigZ   = (float*)(ws + alloc((size_t)N_TOT*512*4));  // Z, then P/preS
    float*  sq     = (float*)(ws + alloc((size_t)N_TOT*4));
    float*  pD     = (float*)(ws + alloc((size_t)N_TOT*NSPLIT*16*4));
    int*    pI     = (int*)  (ws + alloc((size_t)N_TOT*NSPLIT*16*4));
    float*  tD     = (float*)(ws + alloc((size_t)N_TOT*16*4));
    int*    tI     = (int*)  (ws + alloc((size_t)N_TOT*16*4));
    float*  kern   = (float*)(ws + alloc((size_t)N_TOT*16*4));
    float*  deg    = (float*)(ws + alloc((size_t)N_TOT*4));
    float*  dis    = (float*)(ws + alloc((size_t)N_TOT*4));
    int*    cnt    = (int*)  (ws + alloc((size_t)N_TOT*4));
    int*    rowstart=(int*)  (ws + alloc((size_t)(N_TOT+1)*4));
    int*    c2     = (int*)  (ws + alloc((size_t)N_TOT*4));
    int*    in_src = (int*)  (ws + alloc((size_t)N_TOT*16*4));
    float*  in_w   = (float*)(ws + alloc((size_t)N_TOT*16*4));
    float*  out1   = (float*)(ws + alloc((size_t)N_TOT*256*4));
    float*  w2s    = (float*)(ws + alloc((size_t)256*256*4));
    float*  P      = bigZ;                       // alive only after Z is dead
    float*  preS   = bigZ + (size_t)N_TOT*256;

    auto run_stage = [&](const float* H, int d, const float* Bmat, float* outBuf) {
        k_ata<<<dim3(d/32, d/32), dim3(32,32), 0, stream>>>(H, A, d, 1.0);
        for (int p0 = 0; p0 < d; p0 += 64) {
            k_chol_diag<<<1, 256, 0, stream>>>(A, d, p0);
            int rem = d - p0 - 64;
            if (rem > 0) {
                k_trsm<<<(rem+255)/256, 256, 0, stream>>>(A, d, p0);
                k_syrk<<<dim3(rem/64, rem/64), 256, 0, stream>>>(A, d, p0);
            }
        }
        k_linv<<<d, 64, 0, stream>>>(A, W, d);
        k_hw<<<dim3(d/64, N_TOT/64), 256, 0, stream>>>(H, W, bigZ, d);
        k_sq<<<N_TOT/4, 256, 0, stream>>>(bigZ, sq, d);
        k_topk<<<dim3(N_TOT/128, NSPLIT), 256, 0, stream>>>(bigZ, sq, pD, pI, d);
        hipMemsetAsync(sigacc, 0, 8, stream);
        k_merge<<<N_TOT/128, 128, 0, stream>>>(pD, pI, tD, tI, sigacc);
        k_sigfin<<<1, 1, 0, stream>>>(sigacc, inv2s2);
        hipMemsetAsync(deg, 0, N_TOT*4, stream);
        k_kern<<<N_TOT*16/256, 256, 0, stream>>>(tD, tI, inv2s2, kern, deg);
        k_dis<<<N_TOT/256, 256, 0, stream>>>(deg, dis);
        hipMemsetAsync(cnt, 0, N_TOT*4, stream);
        k_count<<<N_TOT*16/256, 256, 0, stream>>>(tI, cnt);
        k_scan<<<1, 1024, 0, stream>>>(cnt, rowstart);
        hipMemsetAsync(c2, 0, N_TOT*4, stream);
        k_fill<<<N_TOT*16/256, 256, 0, stream>>>(tI, kern, rowstart, c2, in_src, in_w);
        // P = H @ Bmat   (Z is dead now; P/preS overlay the Z buffer)
        k_gemm<<<dim3(256/64, N_TOT/64), 256, 0, stream>>>(H, Bmat, P, N_TOT, 256, d, 1.0f);
        // preS = alpha * adj @ P
        k_gemm<<<dim3(256/64, N_TOT/64), 256, 0, stream>>>(adj, P, preS, N_TOT, 256, N_TOT, ALPHA);
        k_spmm_tanh<<<N_TOT, 256, 0, stream>>>(P, preS, kern, tI, dis, rowstart,
                                               in_src, in_w, outBuf);
    };

    run_stage(x, 512, w1, out1);
    k_wsym<<<256, 256, 0, stream>>>(w2, w2s);
    run_stage(out1, 256, w2s, (float*)d_out);
}

// Round 3
// 8046.148 us; speedup vs baseline: 1.4917x; 1.4917x over previous
//
#include <hip/hip_runtime.h>
#include <math.h>
#include <float.h>

#define N_TOT 8192
#define KNB 16
#define ALPHA 0.5f
#define NSPLIT 8
#define CPS (N_TOT/NSPLIT)   // 1024 columns per split

typedef short bf16x8 __attribute__((ext_vector_type(8)));
typedef float f32x4 __attribute__((ext_vector_type(4)));

__device__ inline unsigned short f2bf(float f) {
    unsigned u = __float_as_uint(f);
    u += 0x7fffu + ((u >> 16) & 1u);
    return (unsigned short)(u >> 16);
}
__device__ inline float bf2f(unsigned short h) {
    return __uint_as_float(((unsigned)h) << 16);
}

// ---------------------------------------------------------------------------
// A = beta*I + H^T H  (f64 result, chunked-f32 inner accumulation)
__global__ __launch_bounds__(1024)
void k_ata(const float* __restrict__ H, double* __restrict__ A, int d, double beta) {
    __shared__ float Ha[32][33], Hb[32][33];
    int tx = threadIdx.x, ty = threadIdx.y;
    int a0 = blockIdx.y*32, b0 = blockIdx.x*32;
    double acc = 0.0;
    for (int n0 = 0; n0 < N_TOT; n0 += 32) {
        Ha[ty][tx] = H[(long)(n0+ty)*d + a0+tx];
        Hb[ty][tx] = H[(long)(n0+ty)*d + b0+tx];
        __syncthreads();
        float f = 0.f;
        #pragma unroll
        for (int nn = 0; nn < 32; ++nn)
            f = fmaf(Ha[nn][ty], Hb[nn][tx], f);
        acc += (double)f;
        __syncthreads();
    }
    int a = a0+ty, b = b0+tx;
    A[(long)a*d + b] = acc + ((a==b) ? beta : 0.0);
}

// ---------------------------------------------------------------------------
__global__ __launch_bounds__(256)
void k_chol_diag(double* __restrict__ A, int d, int p0) {
    __shared__ double Ad[64][65];
    int tid = threadIdx.x;
    for (int idx = tid; idx < 64*64; idx += 256) {
        int i = idx>>6, j = idx&63;
        Ad[i][j] = A[(long)(p0+i)*d + p0+j];
    }
    __syncthreads();
    for (int j = 0; j < 64; ++j) {
        if (tid == 0) Ad[j][j] = sqrt(Ad[j][j]);
        __syncthreads();
        for (int i = j+1+tid; i < 64; i += 256) Ad[i][j] /= Ad[j][j];
        __syncthreads();
        for (int idx = tid; idx < 64*64; idx += 256) {
            int i = idx>>6, k = idx&63;
            if (i > j && k > j && k <= i)
                Ad[i][k] -= Ad[i][j]*Ad[k][j];
        }
        __syncthreads();
    }
    for (int idx = tid; idx < 64*64; idx += 256) {
        int i = idx>>6, j = idx&63;
        A[(long)(p0+i)*d + p0+j] = (j <= i) ? Ad[i][j] : 0.0;
    }
}

__global__ __launch_bounds__(256)
void k_trsm(double* __restrict__ A, int d, int p0) {
    __shared__ double Lp[64][65];
    __shared__ double dg[64];
    int tid = threadIdx.x;
    for (int idx = tid; idx < 64*64; idx += 256) {
        int j = idx>>6, k = idx&63;
        double v = A[(long)(p0+j)*d + p0+k];
        Lp[j][k] = (j > k) ? v : 0.0;
        if (j == k) dg[j] = v;
    }
    __syncthreads();
    int r = p0 + 64 + blockIdx.x*256 + tid;
    if (r >= d) return;
    double* Ar = &A[(long)r*d + p0];
    double v[64];
    #pragma unroll
    for (int j = 0; j < 64; ++j) v[j] = Ar[j];
    #pragma unroll
    for (int k = 0; k < 64; ++k) {
        double lr = v[k] / dg[k];
        Ar[k] = lr;
        #pragma unroll
        for (int j = 0; j < 64; ++j) v[j] -= lr * Lp[j][k];
    }
}

__global__ __launch_bounds__(256)
void k_syrk(double* __restrict__ A, int d, int p0) {
    int t0 = p0 + 64;
    int r0 = t0 + blockIdx.y*64, c0 = t0 + blockIdx.x*64;
    __shared__ double Lr[64][33], Lc[64][33];
    int tid = threadIdx.x, tx = tid&15, ty = tid>>4;
    double acc[16];
    #pragma unroll
    for (int i=0;i<16;++i) acc[i]=0.0;
    for (int kc = 0; kc < 64; kc += 32) {
        for (int idx = tid; idx < 64*32; idx += 256) {
            int i = idx>>5, k = idx&31;
            Lr[i][k] = A[(long)(r0+i)*d + p0+kc+k];
            Lc[i][k] = A[(long)(c0+i)*d + p0+kc+k];
        }
        __syncthreads();
        for (int k = 0; k < 32; ++k) {
            double a[4], b[4];
            #pragma unroll
            for (int i=0;i<4;++i){ a[i]=Lr[ty*4+i][k]; b[i]=Lc[tx*4+i][k]; }
            #pragma unroll
            for (int i=0;i<4;++i)
                #pragma unroll
                for (int j=0;j<4;++j) acc[i*4+j] += a[i]*b[j];
        }
        __syncthreads();
    }
    #pragma unroll
    for (int i=0;i<4;++i)
        #pragma unroll
        for (int j=0;j<4;++j)
            A[(long)(r0+ty*4+i)*d + (c0+tx*4+j)] -= acc[i*4+j];
}

__global__ __launch_bounds__(64)
void k_linv(const double* __restrict__ A, double* __restrict__ W, int d) {
    __shared__ double y[512];
    int c = blockIdx.x, lane = threadIdx.x;
    for (int i = lane; i < c; i += 64) W[(long)c*d + i] = 0.0;
    for (int i = lane; i < d; i += 64) y[i] = 0.0;
    __syncthreads();
    for (int i = c; i < d; ++i) {
        const double* Li = &A[(long)i*d];
        double part = 0.0;
        for (int k = c+lane; k < i; k += 64) part += Li[k]*y[k];
        #pragma unroll
        for (int off=32; off>0; off>>=1) part += __shfl_down(part, off);
        if (lane == 0) {
            double yi = (((i==c)?1.0:0.0) - part)/Li[i];
            y[i] = yi;
            W[(long)c*d + i] = yi;
        }
        __syncthreads();
    }
}

// Z = H @ W  (f32 in, f64 W, f64 accumulate, f32 out)
__global__ __launch_bounds__(256)
void k_hw(const float* __restrict__ H, const double* __restrict__ W,
          float* __restrict__ Z, int d) {
    __shared__ __align__(16) float Ht[32][68];
    __shared__ double Wt[32][66];
    int tid = threadIdx.x, tx = tid&15, ty = tid>>4;
    int r0 = blockIdx.y*64, c0 = blockIdx.x*64;
    double acc[4][4];
    #pragma unroll
    for (int i=0;i<4;++i)
        #pragma unroll
        for (int j=0;j<4;++j) acc[i][j]=0.0;
    for (int k0 = 0; k0 < d; k0 += 32) {
        {
            int row = tid>>2, koff = (tid&3)*8;
            const float* src = &H[(long)(r0+row)*d + k0+koff];
            float4 v0 = *(const float4*)src, v1 = *(const float4*)(src+4);
            Ht[koff+0][row]=v0.x; Ht[koff+1][row]=v0.y; Ht[koff+2][row]=v0.z; Ht[koff+3][row]=v0.w;
            Ht[koff+4][row]=v1.x; Ht[koff+5][row]=v1.y; Ht[koff+6][row]=v1.z; Ht[koff+7][row]=v1.w;
        }
        {
            int k = tid>>3, coff = (tid&7)*8;
            const double* src = &W[(long)(k0+k)*d + c0+coff];
            #pragma unroll
            for (int q=0;q<8;++q) Wt[k][coff+q] = src[q];
        }
        __syncthreads();
        #pragma unroll
        for (int k = 0; k < 32; ++k) {
            float4 av = *(const float4*)&Ht[k][ty*4];
            double a0=av.x, a1=av.y, a2=av.z, a3=av.w;
            double b[4];
            #pragma unroll
            for (int j=0;j<4;++j) b[j] = Wt[k][tx*4+j];
            #pragma unroll
            for (int j=0;j<4;++j) {
                acc[0][j] += a0*b[j]; acc[1][j] += a1*b[j];
                acc[2][j] += a2*b[j]; acc[3][j] += a3*b[j];
            }
        }
        __syncthreads();
    }
    #pragma unroll
    for (int i=0;i<4;++i)
        #pragma unroll
        for (int j=0;j<4;++j)
            Z[(long)(r0+ty*4+i)*d + c0+tx*4+j] = (float)acc[i][j];
}

__global__ __launch_bounds__(256)
void k_sq(const float* __restrict__ Z, float* __restrict__ sq, int d) {
    int row = blockIdx.x*4 + (threadIdx.x>>6);
    int lane = threadIdx.x&63;
    const float* z = &Z[(long)row*d];
    double s = 0.0;
    for (int c = lane; c < d; c += 64) { float v = z[c]; s += (double)v*v; }
    #pragma unroll
    for (int off=32; off>0; off>>=1) s += __shfl_down(s, off);
    if (lane==0) sq[row] = (float)s;
}

// Z (f32) -> Zh + Zl (bf16 split)
__global__ __launch_bounds__(256)
void k_zsplit(const float* __restrict__ Z, unsigned short* __restrict__ Zh,
              unsigned short* __restrict__ Zl, long n) {
    long i = ((long)blockIdx.x*256 + threadIdx.x)*8;
    if (i >= n) return;
    float4 v0 = *(const float4*)&Z[i], v1 = *(const float4*)&Z[i+4];
    float z[8] = {v0.x,v0.y,v0.z,v0.w,v1.x,v1.y,v1.z,v1.w};
    __align__(16) unsigned short h[8], l[8];
    #pragma unroll
    for (int j=0;j<8;++j) {
        h[j] = f2bf(z[j]);
        l[j] = f2bf(z[j] - bf2f(h[j]));
    }
    *(uint4*)&Zh[i] = *(const uint4*)h;
    *(uint4*)&Zl[i] = *(const uint4*)l;
}

// ---------------------------------------------------------------------------
// Fused split-bf16 MFMA distance GEMM + per-row top-16.
// grid (N/128, NSPLIT), block 256 (4 waves). 128 rows x 1024 cols per block.
__global__ __launch_bounds__(256)
void k_topk_mfma(const unsigned short* __restrict__ Zh, const unsigned short* __restrict__ Zl,
                 const float* __restrict__ sq,
                 float* __restrict__ pD, int* __restrict__ pI, int d) {
    __shared__ unsigned short Ah[128*40], Al[128*40], Bh[128*40], Bl[128*40];
    __shared__ float d2s[128][33];
    __shared__ float topD[128][16];
    __shared__ int   topI[128][16];
    __shared__ float thrS[128];
    int tid = threadIdx.x;
    int wid = tid>>6, lane = tid&63;
    int lr = lane&15, kg = lane>>4;
    int r0 = blockIdx.x*128;
    int split = blockIdx.y;
    for (int idx = tid; idx < 128*16; idx += 256) {
        topD[idx>>4][idx&15] = FLT_MAX;
        topI[idx>>4][idx&15] = 0x7fffffff;
    }
    if (tid < 128) thrS[tid] = FLT_MAX;

    int srow = tid>>1, shalf = tid&1;
    // per-thread output-row sq values (fixed across chunks)
    float srr[2][4];
    #pragma unroll
    for (int fr=0; fr<2; ++fr)
        #pragma unroll
        for (int q=0; q<4; ++q)
            srr[fr][q] = sq[r0 + wid*32 + fr*16 + kg*4 + q];

    for (int ch = 0; ch < CPS/128; ++ch) {
        int c0 = split*CPS + ch*128;
        f32x4 acc[2][8];
        #pragma unroll
        for (int fr=0; fr<2; ++fr)
            #pragma unroll
            for (int fc=0; fc<8; ++fc)
                acc[fr][fc] = (f32x4){0.f,0.f,0.f,0.f};

        for (int k0 = 0; k0 < d; k0 += 32) {
            __syncthreads();   // prior reads of staging done
            {
                // each of 2 threads/row stages 16 bf16 (full 32/row coverage)
                long ga = (long)(r0+srow)*d + k0 + shalf*16;
                uint4 vh0 = *(const uint4*)&Zh[ga];
                uint4 vh1 = *(const uint4*)&Zh[ga+8];
                uint4 vl0 = *(const uint4*)&Zl[ga];
                uint4 vl1 = *(const uint4*)&Zl[ga+8];
                *(uint4*)&Ah[srow*40 + shalf*16]     = vh0;
                *(uint4*)&Ah[srow*40 + shalf*16 + 8] = vh1;
                *(uint4*)&Al[srow*40 + shalf*16]     = vl0;
                *(uint4*)&Al[srow*40 + shalf*16 + 8] = vl1;
                long gb = (long)(c0+srow)*d + k0 + shalf*16;
                uint4 wh0 = *(const uint4*)&Zh[gb];
                uint4 wh1 = *(const uint4*)&Zh[gb+8];
                uint4 wl0 = *(const uint4*)&Zl[gb];
                uint4 wl1 = *(const uint4*)&Zl[gb+8];
                *(uint4*)&Bh[srow*40 + shalf*16]     = wh0;
                *(uint4*)&Bh[srow*40 + shalf*16 + 8] = wh1;
                *(uint4*)&Bl[srow*40 + shalf*16]     = wl0;
                *(uint4*)&Bl[srow*40 + shalf*16 + 8] = wl1;
            }
            __syncthreads();
            bf16x8 ah[2], al[2];
            #pragma unroll
            for (int fr=0; fr<2; ++fr) {
                int ar = wid*32 + fr*16 + lr;
                ah[fr] = *(const bf16x8*)&Ah[ar*40 + kg*8];
                al[fr] = *(const bf16x8*)&Al[ar*40 + kg*8];
            }
            #pragma unroll
            for (int fc=0; fc<8; ++fc) {
                int br = fc*16 + lr;
                bf16x8 bh = *(const bf16x8*)&Bh[br*40 + kg*8];
                bf16x8 bl = *(const bf16x8*)&Bl[br*40 + kg*8];
                #pragma unroll
                for (int fr=0; fr<2; ++fr) {
                    acc[fr][fc] = __builtin_amdgcn_mfma_f32_16x16x32_bf16(ah[fr], bh, acc[fr][fc], 0,0,0);
                    acc[fr][fc] = __builtin_amdgcn_mfma_f32_16x16x32_bf16(ah[fr], bl, acc[fr][fc], 0,0,0);
                    acc[fr][fc] = __builtin_amdgcn_mfma_f32_16x16x32_bf16(al[fr], bh, acc[fr][fc], 0,0,0);
                }
            }
        }
        // selection: 4 slices of 32 columns
        #pragma unroll
        for (int s=0; s<4; ++s) {
            __syncthreads();   // previous slice's scan done / GEMM done
            #pragma unroll
            for (int f=0; f<2; ++f) {
                int fc = 2*s+f;
                float sc = sq[c0 + fc*16 + lr];
                #pragma unroll
                for (int fr=0; fr<2; ++fr) {
                    #pragma unroll
                    for (int q=0; q<4; ++q) {
                        int rloc = wid*32 + fr*16 + kg*4 + q;
                        d2s[rloc][f*16 + lr] = srr[fr][q] + sc - 2.f*acc[fr][fc][q];
                    }
                }
            }
            __syncthreads();
            if (tid < 128) {
                int r = tid;
                int c0s = c0 + s*32;
                float th = thrS[r];
                for (int j = 0; j < 32; ++j) {
                    float dv = d2s[r][j];
                    int ci = c0s + j;
                    bool ins = (dv < th) || (dv == th && ci < topI[r][15]);
                    if (ins) {
                        int pos = 15;
                        while (pos > 0) {
                            float pd_ = topD[r][pos-1]; int pi_ = topI[r][pos-1];
                            if (dv < pd_ || (dv == pd_ && ci < pi_)) {
                                topD[r][pos] = pd_; topI[r][pos] = pi_; --pos;
                            } else break;
                        }
                        topD[r][pos] = dv; topI[r][pos] = ci;
                        th = topD[r][15];
                    }
                }
                thrS[r] = th;
            }
        }
    }
    __syncthreads();
    for (int idx = tid; idx < 128*16; idx += 256) {
        int r = idx>>4, k = idx&15;
        long o = ((long)(r0+r)*NSPLIT + split)*16 + k;
        pD[o] = topD[r][k]; pI[o] = topI[r][k];
    }
}

// ---------------------------------------------------------------------------
__global__ __launch_bounds__(128)
void k_merge(const float* __restrict__ pD, const int* __restrict__ pI,
             float* __restrict__ tD, int* __restrict__ tI, double* sig_accum) {
    __shared__ float mD[128][17];
    __shared__ int   mI[128][17];
    __shared__ double red[128];
    int tid = threadIdx.x;
    long row = (long)blockIdx.x*128 + tid;
    #pragma unroll
    for (int k=0;k<16;++k){ mD[tid][k]=FLT_MAX; mI[tid][k]=0x7fffffff; }
    for (int s = 0; s < NSPLIT; ++s) {
        const float* pd = &pD[(row*NSPLIT+s)*16];
        const int*   pi = &pI[(row*NSPLIT+s)*16];
        for (int k = 0; k < 16; ++k) {
            float dv = pd[k]; int ci = pi[k];
            float wd = mD[tid][15]; int wi = mI[tid][15];
            if (dv > wd || (dv == wd && ci > wi)) break;
            int pos = 15;
            while (pos > 0 && (dv < mD[tid][pos-1] ||
                   (dv == mD[tid][pos-1] && ci < mI[tid][pos-1]))) {
                mD[tid][pos]=mD[tid][pos-1]; mI[tid][pos]=mI[tid][pos-1]; --pos;
            }
            mD[tid][pos]=dv; mI[tid][pos]=ci;
        }
    }
    double psum = 0.0;
    #pragma unroll
    for (int k=0;k<16;++k) {
        float dv = mD[tid][k];
        tD[row*16+k]=dv; tI[row*16+k]=mI[tid][k];
        psum += sqrt((double)fmaxf(dv, 0.f));
    }
    red[tid]=psum; __syncthreads();
    for (int s=64;s>0;s>>=1){ if(tid<s) red[tid]+=red[tid+s]; __syncthreads(); }
    if (tid==0) atomicAdd(sig_accum, red[0]);
}

__global__ void k_sigfin(const double* __restrict__ sig_accum, float* __restrict__ inv2s2) {
    double s = sig_accum[0] / (double)(N_TOT*KNB);
    inv2s2[0] = (float)(1.0/(2.0*s*s));
}

__global__ __launch_bounds__(256)
void k_kern(const float* __restrict__ tD, const int* __restrict__ tI,
            const float* __restrict__ inv2s2,
            float* __restrict__ kern, float* __restrict__ deg) {
    int e = blockIdx.x*256 + threadIdx.x;
    int i = e>>4;
    float d2 = fmaxf(tD[e], 0.f);
    float kv = expf(-d2 * inv2s2[0]);
    kern[e] = kv;
    atomicAdd(&deg[i], 0.5f*kv);
    atomicAdd(&deg[tI[e]], 0.5f*kv);
}

__global__ __launch_bounds__(256)
void k_dis(const float* __restrict__ deg, float* __restrict__ dis) {
    int i = blockIdx.x*256 + threadIdx.x;
    float v = deg[i];
    dis[i] = (v > 0.f) ? (1.0f/sqrtf(v)) : 0.f;
}

__global__ __launch_bounds__(256)
void k_count(const int* __restrict__ tI, int* __restrict__ cnt) {
    int e = blockIdx.x*256 + threadIdx.x;
    atomicAdd(&cnt[tI[e]], 1);
}

__global__ __launch_bounds__(1024)
void k_scan(const int* __restrict__ cnt, int* __restrict__ rowstart) {
    __shared__ int buf[1024];
    __shared__ int carry;
    int tid = threadIdx.x;
    if (tid==0) carry = 0;
    __syncthreads();
    for (int base = 0; base < N_TOT; base += 1024) {
        int v = cnt[base+tid];
        buf[tid]=v; __syncthreads();
        for (int off=1; off<1024; off<<=1) {
            int t = (tid>=off)? buf[tid-off] : 0; __syncthreads();
            buf[tid]+=t; __syncthreads();
        }
        rowstart[base+tid] = carry + buf[tid] - v;
        __syncthreads();
        if (tid==1023) carry += buf[1023];
        __syncthreads();
    }
    if (tid==0) rowstart[N_TOT] = carry;
}

__global__ __launch_bounds__(256)
void k_fill(const int* __restrict__ tI, const float* __restrict__ kern,
            const int* __restrict__ rowstart, int* __restrict__ c2,
            int* __restrict__ in_src, float* __restrict__ in_w) {
    int e = blockIdx.x*256 + threadIdx.x;
    int i = e>>4;
    int j = tI[e];
    int pos = atomicAdd(&c2[j], 1);
    int dst = rowstart[j] + pos;
    in_src[dst] = i; in_w[dst] = kern[e];
}

// generic f32 C = scale*(A@B), used for P = H @ Bmat (small K)
__global__ __launch_bounds__(256)
void k_gemm(const float* __restrict__ A, const float* __restrict__ B,
            float* __restrict__ C, int M, int N, int Kd, float scale) {
    __shared__ __align__(16) float At[16][68];
    __shared__ __align__(16) float Bt[16][68];
    int tid = threadIdx.x, tx = tid&15, ty = tid>>4;
    int r0 = blockIdx.y*64, c0 = blockIdx.x*64;
    float acc[4][4];
    #pragma unroll
    for (int i=0;i<4;++i)
        #pragma unroll
        for (int j=0;j<4;++j) acc[i][j]=0.f;
    for (int k0 = 0; k0 < Kd; k0 += 16) {
        {
            int row = tid>>2, koff = (tid&3)*4;
            float4 v = *(const float4*)&A[(long)(r0+row)*Kd + k0+koff];
            At[koff+0][row]=v.x; At[koff+1][row]=v.y; At[koff+2][row]=v.z; At[koff+3][row]=v.w;
        }
        {
            int k = tid>>4, coff = (tid&15)*4;
            float4 v = *(const float4*)&B[(long)(k0+k)*N + c0+coff];
            *(float4*)&Bt[k][coff] = v;
        }
        __syncthreads();
        #pragma unroll
        for (int k=0;k<16;++k) {
            float4 a = *(const float4*)&At[k][ty*4];
            float4 b = *(const float4*)&Bt[k][tx*4];
            float ar[4] = {a.x,a.y,a.z,a.w};
            float br[4] = {b.x,b.y,b.z,b.w};
            #pragma unroll
            for (int i=0;i<4;++i)
                #pragma unroll
                for (int j=0;j<4;++j) acc[i][j] = fmaf(ar[i], br[j], acc[i][j]);
        }
        __syncthreads();
    }
    #pragma unroll
    for (int i=0;i<4;++i)
        #pragma unroll
        for (int j=0;j<4;++j)
            C[(long)(r0+ty*4+i)*N + c0+tx*4+j] = scale*acc[i][j];
}

// P [8192][256] f32 -> PTh/PTl [256][8192] bf16 split (transpose + convert)
__global__ __launch_bounds__(256)
void k_prepPT(const float* __restrict__ P, unsigned short* __restrict__ PTh,
              unsigned short* __restrict__ PTl) {
    __shared__ float tile[64][65];
    int r0 = blockIdx.y*64;   // P rows
    int c0 = blockIdx.x*64;   // P cols
    int t = threadIdx.x;
    {
        int row = t>>2, cseg = t&3;
        #pragma unroll
        for (int i=0;i<4;++i) {
            float4 v = *(const float4*)&P[(long)(r0+row)*256 + c0 + cseg*16 + i*4];
            tile[row][cseg*16+i*4+0]=v.x; tile[row][cseg*16+i*4+1]=v.y;
            tile[row][cseg*16+i*4+2]=v.z; tile[row][cseg*16+i*4+3]=v.w;
        }
    }
    __syncthreads();
    {
        int col = t>>2, rseg = t&3;
        __align__(16) unsigned short hs[16], ls[16];
        #pragma unroll
        for (int i=0;i<16;++i) {
            float z = tile[rseg*16+i][col];
            hs[i] = f2bf(z);
            ls[i] = f2bf(z - bf2f(hs[i]));
        }
        long addr = (long)(c0+col)*N_TOT + r0 + rseg*16;
        *(uint4*)&PTh[addr]   = *(const uint4*)&hs[0];
        *(uint4*)&PTh[addr+8] = *(const uint4*)&hs[8];
        *(uint4*)&PTl[addr]   = *(const uint4*)&ls[0];
        *(uint4*)&PTl[addr+8] = *(const uint4*)&ls[8];
    }
}

// C[8192][256] = scale * adj @ P via split-bf16 MFMA. adj converted in staging.
// grid 256 blocks (32 rows each), block 256 (4 waves, each 32x64 cols).
__global__ __launch_bounds__(256)
void k_adjP(const float* __restrict__ adj, const unsigned short* __restrict__ PTh,
            const unsigned short* __restrict__ PTl, float* __restrict__ C, float scale) {
    __shared__ unsigned short Ah[32*40], Al[32*40];
    __shared__ unsigned short Bh[256*40], Bl[256*40];
    int tid = threadIdx.x, wid = tid>>6, lane = tid&63;
    int lr = lane&15, kg = lane>>4;
    int r0 = blockIdx.x*32;
    f32x4 acc[2][4];
    #pragma unroll
    for (int fr=0; fr<2; ++fr)
        #pragma unroll
        for (int fc=0; fc<4; ++fc)
            acc[fr][fc] = (f32x4){0.f,0.f,0.f,0.f};
    int arow = tid>>3, aseg = tid&7;
    for (int k0 = 0; k0 < N_TOT; k0 += 32) {
        __syncthreads();
        {
            float4 v = *(const float4*)&adj[(long)(r0+arow)*N_TOT + k0 + aseg*4];
            float z[4] = {v.x, v.y, v.z, v.w};
            __align__(8) unsigned short h[4], l[4];
            #pragma unroll
            for (int j=0;j<4;++j) {
                h[j] = f2bf(z[j]);
                l[j] = f2bf(z[j] - bf2f(h[j]));
            }
            *(ushort4*)&Ah[arow*40 + aseg*4] = *(const ushort4*)h;
            *(ushort4*)&Al[arow*40 + aseg*4] = *(const ushort4*)l;
        }
        {
            long gb = (long)tid*N_TOT + k0;
            #pragma unroll
            for (int q=0;q<4;++q) {
                uint4 vh = *(const uint4*)&PTh[gb + q*8];
                uint4 vl = *(const uint4*)&PTl[gb + q*8];
                *(uint4*)&Bh[tid*40 + q*8] = vh;
                *(uint4*)&Bl[tid*40 + q*8] = vl;
            }
        }
        __syncthreads();
        bf16x8 ah[2], al[2];
        #pragma unroll
        for (int fr=0; fr<2; ++fr) {
            int ar = fr*16 + lr;
            ah[fr] = *(const bf16x8*)&Ah[ar*40 + kg*8];
            al[fr] = *(const bf16x8*)&Al[ar*40 + kg*8];
        }
        #pragma unroll
        for (int fc=0; fc<4; ++fc) {
            int br = wid*64 + fc*16 + lr;
            bf16x8 bh = *(const bf16x8*)&Bh[br*40 + kg*8];
            bf16x8 bl = *(const bf16x8*)&Bl[br*40 + kg*8];
            #pragma unroll
            for (int fr=0; fr<2; ++fr) {
                acc[fr][fc] = __builtin_amdgcn_mfma_f32_16x16x32_bf16(ah[fr], bh, acc[fr][fc], 0,0,0);
                acc[fr][fc] = __builtin_amdgcn_mfma_f32_16x16x32_bf16(ah[fr], bl, acc[fr][fc], 0,0,0);
                acc[fr][fc] = __builtin_amdgcn_mfma_f32_16x16x32_bf16(al[fr], bh, acc[fr][fc], 0,0,0);
            }
        }
    }
    #pragma unroll
    for (int fr=0; fr<2; ++fr)
        #pragma unroll
        for (int fc=0; fc<4; ++fc)
            #pragma unroll
            for (int q=0; q<4; ++q) {
                int rg = r0 + fr*16 + kg*4 + q;
                int cg = wid*64 + fc*16 + lr;
                C[(long)rg*256 + cg] = scale*acc[fr][fc][q];
            }
}

__global__ __launch_bounds__(256)
void k_wsym(const float* __restrict__ w2, float* __restrict__ w2s) {
    int i = blockIdx.x, j = threadIdx.x;
    w2s[i*256+j] = 0.5f*(w2[i*256+j] + w2[j*256+i]);
}

__global__ __launch_bounds__(256)
void k_spmm_tanh(const float* __restrict__ P, const float* __restrict__ preS,
                 const float* __restrict__ kern, const int* __restrict__ tI,
                 const float* __restrict__ dis, const int* __restrict__ rowstart,
                 const int* __restrict__ in_src, const float* __restrict__ in_w,
                 float* __restrict__ out) {
    int i = blockIdx.x, c = threadIdx.x;
    float acc = 0.f;
    float di = dis[i];
    #pragma unroll 1
    for (int k = 0; k < 16; ++k) {
        int e = i*16+k;
        int j = tI[e];
        float w = 0.5f*kern[e]*dis[j];
        acc = fmaf(w, P[(long)j*256 + c], acc);
    }
    int s0 = rowstart[i], s1 = rowstart[i+1];
    for (int t = s0; t < s1; ++t) {
        int j = in_src[t];
        float w = 0.5f*in_w[t]*dis[j];
        acc = fmaf(w, P[(long)j*256 + c], acc);
    }
    float pre = preS[(long)i*256+c] + di*acc;
    out[(long)i*256+c] = tanhf(pre);
}

// ---------------------------------------------------------------------------
extern "C" void kernel_launch(void* const* d_in, const int* in_sizes, int n_in,
                              void* d_out, int out_size, void* d_ws, size_t ws_size,
                              hipStream_t stream) {
    const float* x   = (const float*)d_in[0];
    const float* adj = (const float*)d_in[1];
    const float* w1  = (const float*)d_in[2];
    const float* w2  = (const float*)d_in[3];

    char* ws = (char*)d_ws;
    size_t off = 0;
    auto alloc = [&](size_t bytes){ size_t o = off; off += (bytes+255)&~(size_t)255; return o; };
    double* A      = (double*)(ws + alloc((size_t)512*512*8));
    double* W      = (double*)(ws + alloc((size_t)512*512*8));
    double* sigacc = (double*)(ws + alloc(256));
    float*  inv2s2 = (float*)(ws + alloc(256));
    float*  bigZ   = (float*)(ws + alloc((size_t)N_TOT*512*4));  // Z, then P/preS
    unsigned short* Zh = (unsigned short*)(ws + alloc((size_t)N_TOT*512*2));
    unsigned short* Zl = (unsigned short*)(ws + alloc((size_t)N_TOT*512*2));
    unsigned short* PTh = (unsigned short*)(ws + alloc((size_t)256*N_TOT*2));
    unsigned short* PTl = (unsigned short*)(ws + alloc((size_t)256*N_TOT*2));
    float*  sq     = (float*)(ws + alloc((size_t)N_TOT*4));
    float*  pD     = (float*)(ws + alloc((size_t)N_TOT*NSPLIT*16*4));
    int*    pI     = (int*)  (ws + alloc((size_t)N_TOT*NSPLIT*16*4));
    float*  tD     = (float*)(ws + alloc((size_t)N_TOT*16*4));
    int*    tI     = (int*)  (ws + alloc((size_t)N_TOT*16*4));
    float*  kern   = (float*)(ws + alloc((size_t)N_TOT*16*4));
    float*  deg    = (float*)(ws + alloc((size_t)N_TOT*4));
    float*  dis    = (float*)(ws + alloc((size_t)N_TOT*4));
    int*    cnt    = (int*)  (ws + alloc((size_t)N_TOT*4));
    int*    rowstart=(int*)  (ws + alloc((size_t)(N_TOT+1)*4));
    int*    c2     = (int*)  (ws + alloc((size_t)N_TOT*4));
    int*    in_src = (int*)  (ws + alloc((size_t)N_TOT*16*4));
    float*  in_w   = (float*)(ws + alloc((size_t)N_TOT*16*4));
    float*  out1   = (float*)(ws + alloc((size_t)N_TOT*256*4));
    float*  w2s    = (float*)(ws + alloc((size_t)256*256*4));
    float*  P      = bigZ;                       // overlays Z after Z is dead
    float*  preS   = bigZ + (size_t)N_TOT*256;

    auto run_stage = [&](const float* H, int d, const float* Bmat, float* outBuf) {
        k_ata<<<dim3(d/32, d/32), dim3(32,32), 0, stream>>>(H, A, d, 1.0);
        for (int p0 = 0; p0 < d; p0 += 64) {
            k_chol_diag<<<1, 256, 0, stream>>>(A, d, p0);
            int rem = d - p0 - 64;
            if (rem > 0) {
                k_trsm<<<(rem+255)/256, 256, 0, stream>>>(A, d, p0);
                k_syrk<<<dim3(rem/64, rem/64), 256, 0, stream>>>(A, d, p0);
            }
        }
        k_linv<<<d, 64, 0, stream>>>(A, W, d);
        k_hw<<<dim3(d/64, N_TOT/64), 256, 0, stream>>>(H, W, bigZ, d);
        k_sq<<<N_TOT/4, 256, 0, stream>>>(bigZ, sq, d);
        k_zsplit<<<(int)(((long)N_TOT*d)/(256*8)), 256, 0, stream>>>(bigZ, Zh, Zl, (long)N_TOT*d);
        k_topk_mfma<<<dim3(N_TOT/128, NSPLIT), 256, 0, stream>>>(Zh, Zl, sq, pD, pI, d);
        hipMemsetAsync(sigacc, 0, 8, stream);
        k_merge<<<N_TOT/128, 128, 0, stream>>>(pD, pI, tD, tI, sigacc);
        k_sigfin<<<1, 1, 0, stream>>>(sigacc, inv2s2);
        hipMemsetAsync(deg, 0, N_TOT*4, stream);
        k_kern<<<N_TOT*16/256, 256, 0, stream>>>(tD, tI, inv2s2, kern, deg);
        k_dis<<<N_TOT/256, 256, 0, stream>>>(deg, dis);
        hipMemsetAsync(cnt, 0, N_TOT*4, stream);
        k_count<<<N_TOT*16/256, 256, 0, stream>>>(tI, cnt);
        k_scan<<<1, 1024, 0, stream>>>(cnt, rowstart);
        hipMemsetAsync(c2, 0, N_TOT*4, stream);
        k_fill<<<N_TOT*16/256, 256, 0, stream>>>(tI, kern, rowstart, c2, in_src, in_w);
        // P = H @ Bmat  (Z dead now; P/preS overlay Z buffer)
        k_gemm<<<dim3(256/64, N_TOT/64), 256, 0, stream>>>(H, Bmat, P, N_TOT, 256, d, 1.0f);
        // preS = ALPHA * adj @ P via split-bf16 MFMA
        k_prepPT<<<dim3(4, N_TOT/64), 256, 0, stream>>>(P, PTh, PTl);
        k_adjP<<<N_TOT/32, 256, 0, stream>>>(adj, PTh, PTl, preS, ALPHA);
        k_spmm_tanh<<<N_TOT, 256, 0, stream>>>(P, preS, kern, tI, dis, rowstart,
                                               in_src, in_w, outBuf);
    };

    run_stage(x, 512, w1, out1);
    k_wsym<<<256, 256, 0, stream>>>(w2, w2s);
    run_stage(out1, 256, w2s, (float*)d_out);
}